// Round 17
// baseline (435.229 us; speedup 1.0000x reference)
//
#include <hip/hip_runtime.h>

typedef unsigned int uint;
typedef unsigned short ushort_t;
typedef unsigned long long u64;
typedef __attribute__((ext_vector_type(4))) float f32x4;
typedef __attribute__((ext_vector_type(8))) __bf16 bf16x8;
typedef __attribute__((ext_vector_type(8))) unsigned short us8;

#define BATCH 65536
#define VEC 512
#define K 1024
#define GAMMA 0.99f
#define EPS 1e-05f
#define SEG 32
#define MARGIN 0.75f

// GEMM geometry: 256x256 tile, BK=64, 8 waves (2M x 4N), per-wave 128x64
#define NKT (VEC / 64)      // 8 K-tiles
#define TG 2048             // granules per K-tile per operand

// round-to-nearest-even f32 -> bf16
__device__ __forceinline__ ushort_t rtn(float f) {
    uint u = __float_as_uint(f);
    return (ushort_t)((u + 0x7FFFu + ((u >> 16) & 1u)) >> 16);
}

__device__ __forceinline__ void gl16(const void* g, void* l) {
    __builtin_amdgcn_global_load_lds(
        (const __attribute__((address_space(1))) unsigned int*)g,
        (__attribute__((address_space(3))) unsigned int*)l, 16, 0, 0);
}

__device__ __forceinline__ float dec_key(uint e) {
    uint b = (e & 0x80000000u) ? (e & 0x7FFFFFFFu) : ~e;
    return __uint_as_float(b);
}

#define BC8(p) __builtin_bit_cast(bf16x8, (p))

// ---- pack w only: B granules [gx 4][kt 8][g 2048] + wT + w2 partials + inits
// granule g = ct*128 + ksub*64 + lane: col = gx*256+ct*16+(lane&15),
//   k = kt*64 + ksub*32 + (lane>>4)*8 + j
__global__ void k_pack(const float* __restrict__ w, us8* __restrict__ wpk,
                       float* __restrict__ wT, float* __restrict__ w2p,
                       int* __restrict__ cc /* counts|cursor: 2048 ints */) {
    __shared__ float lds[32][257];
    const int b = blockIdx.x;            // 32 blocks: gx*8 + kt
    const int gx = b >> 3, kt = b & 7;
    const int t = threadIdx.x;

    float s = 0.f;
#pragma unroll
    for (int ih = 0; ih < 2; ++ih) {
        __syncthreads();
#pragma unroll
        for (int r = 0; r < 32; ++r)
            lds[r][t] = w[(size_t)(kt * 64 + ih * 32 + r) * K + gx * 256 + t];
        __syncthreads();

#pragma unroll
        for (int r = 0; r < 32; ++r) { float f = lds[r][t]; s += f * f; }

#pragma unroll
        for (int i = 0; i < 4; ++i) {
            const int c = i * 256 + t;
            const int ct = c >> 6, lane = c & 63;
            const int cl = ct * 16 + (lane & 15);
            const int r0 = (lane >> 4) * 8;
            us8 v;
#pragma unroll
            for (int j = 0; j < 8; ++j) v[j] = rtn(lds[r0 + j][cl]);
            wpk[(size_t)b * TG + ct * 128 + ih * 64 + lane] = v;
        }

#pragma unroll
        for (int rr = 0; rr < 8; ++rr) {
            f32x4 v = {lds[rr * 4 + 0][t], lds[rr * 4 + 1][t],
                       lds[rr * 4 + 2][t], lds[rr * 4 + 3][t]};
            *(f32x4*)&wT[(size_t)(gx * 256 + t) * VEC + kt * 64 + ih * 32 + rr * 4] = v;
        }
    }
    w2p[kt * K + gx * 256 + t] = s;

    if (b < 8) cc[b * 256 + t] = 0;
}

// ---- main: 256x256 BK=64 MFMA distance GEMM; A reg-staged from x (f32->rtn),
// B via counted-vmcnt gl16 from packed wpk. Issue order A-before-B per tile so
// the compiler's A-reg wait is vmcnt(4) (B stays in flight). 2 phases/kt.
__launch_bounds__(512, 2)
__global__ void k_gemm(const float* __restrict__ x, const us8* __restrict__ wpk,
                       const float* __restrict__ w2p,
                       u64* __restrict__ keysA, u64* __restrict__ keysB) {
    __shared__ us8 lds[2][2 * TG];   // [0..2047]=A, [2048..4095]=B; 128 KB

    const int blk = blockIdx.x;
    // XCD-chunked bijection (1024 % 8 == 0)
    const int ord = blk >> 3;
    const int gy = (blk & 7) * 32 + (ord >> 2);
    const int gx = ord & 3;
    const int t = threadIdx.x;
    const int lane = t & 63;
    const int wv = t >> 6;
    const int wm = wv >> 2;      // 0..1 (128 rows)
    const int wn = wv & 3;       // 0..3 (64 cols)

    const us8* bsrc = wpk + (size_t)gx * (NKT * TG);

    f32x4 av[4][2];
    auto aload = [&](int kt) {
#pragma unroll
        for (int i = 0; i < 4; ++i) {
            const int g = t + i * 512;
            const int row = gy * 256 + (g >> 7) * 16 + (g & 15);
            const int k = kt * 64 + ((g >> 6) & 1) * 32 + (((g >> 4) & 3) << 3);
            const float* p = x + (size_t)row * VEC + k;
            av[i][0] = *(const f32x4*)p;
            av[i][1] = *(const f32x4*)(p + 4);
        }
    };
    auto awrite = [&](int slot) {
#pragma unroll
        for (int i = 0; i < 4; ++i) {
            us8 v;
#pragma unroll
            for (int j = 0; j < 4; ++j) { v[j] = rtn(av[i][0][j]); v[4 + j] = rtn(av[i][1][j]); }
            lds[slot][t + i * 512] = v;
        }
    };
    auto bstage = [&](int slot, int kt) {
        const us8* sb = bsrc + (size_t)kt * TG;
#pragma unroll
        for (int i = 0; i < 4; ++i) gl16(sb + i * 512 + t, &lds[slot][TG + i * 512 + t]);
    };

    f32x4 acc[8][4];
#pragma unroll
    for (int i = 0; i < 8; ++i)
#pragma unroll
        for (int j = 0; j < 4; ++j) acc[i][j] = (f32x4){0.f, 0.f, 0.f, 0.f};

    // prologue: queue order [B0, A1, B1] entering the loop
    aload(0);
    bstage(0, 0);
    awrite(0);                       // compiler waits A0 (vmcnt(4)); B0 in flight
    aload(1);
    bstage(1, 1);
    asm volatile("s_waitcnt lgkmcnt(0)" ::: "memory");   // awrite(0) ds_writes done

    for (int kt = 0; kt < NKT; ++kt) {
        const int buf = kt & 1;
        if (kt >= 1 && kt + 1 < NKT) {
            aload(kt + 1);               // 8 vmem (regs) -- BEFORE B gl16
            bstage(buf ^ 1, kt + 1);     // 4 vmem (lds)
            asm volatile("s_waitcnt vmcnt(12)" ::: "memory");  // drain B(kt)
        } else if (kt == 0) {
            asm volatile("s_waitcnt vmcnt(12)" ::: "memory");  // drain B0
        } else {
            asm volatile("s_waitcnt vmcnt(0)" ::: "memory");   // last tile
        }
        __builtin_amdgcn_s_barrier();    // staging of tile kt visible

#pragma unroll
        for (int ph = 0; ph < 2; ++ph) {
            const int kb = ph * 64;
            bf16x8 ah[8], bh[4];
#pragma unroll
            for (int rt = 0; rt < 8; ++rt)
                ah[rt] = BC8(lds[buf][(wm * 8 + rt) * 128 + kb + lane]);
#pragma unroll
            for (int ct = 0; ct < 4; ++ct)
                bh[ct] = BC8(lds[buf][TG + (wn * 4 + ct) * 128 + kb + lane]);
            __builtin_amdgcn_s_barrier();
            asm volatile("s_waitcnt lgkmcnt(0)" ::: "memory");
            __builtin_amdgcn_sched_barrier(0);
            __builtin_amdgcn_s_setprio(1);
#pragma unroll
            for (int rt = 0; rt < 8; ++rt)
#pragma unroll
                for (int ct = 0; ct < 4; ++ct)
                    acc[rt][ct] = __builtin_amdgcn_mfma_f32_16x16x32_bf16(ah[rt], bh[ct], acc[rt][ct], 0, 0, 0);
            __builtin_amdgcn_s_setprio(0);
            __builtin_amdgcn_s_barrier();
        }

        if (kt + 1 < NKT) awrite(buf ^ 1);   // waits A(kt+1) at vmcnt(4); B(kt+1) in flight
        asm volatile("s_waitcnt lgkmcnt(0)" ::: "memory");
        __builtin_amdgcn_s_barrier();        // publish A(kt+1)
    }

    // epilogue: dist = w2 - 2*dot; per-row TOP-2 over wave's 64 cols; slot store
    const int col_base = gx * 256 + wn * 64;
    float w2c[4];
#pragma unroll
    for (int ct = 0; ct < 4; ++ct) {
        const int col = col_base + ct * 16 + (lane & 15);
        float s = 0.f;
#pragma unroll
        for (int p = 0; p < 8; ++p) s += w2p[p * K + col];
        w2c[ct] = s;
    }
    const int slot = gx * 4 + wn;

#pragma unroll
    for (int rt = 0; rt < 8; ++rt) {
#pragma unroll
        for (int reg = 0; reg < 4; ++reg) {
            u64 k1 = ~0ull, k2 = ~0ull;
#pragma unroll
            for (int ct = 0; ct < 4; ++ct) {
                float dist = w2c[ct] - 2.0f * acc[rt][ct][reg];
                uint su = __float_as_uint(dist);
                su = (su & 0x80000000u) ? ~su : (su | 0x80000000u);
                const u64 key = ((u64)su << 32) | (uint)(col_base + ct * 16 + (lane & 15));
                if (key < k1) { k2 = k1; k1 = key; }
                else if (key < k2) { k2 = key; }
            }
#pragma unroll
            for (int m = 1; m < 16; m <<= 1) {
                u64 o1 = __shfl_xor((unsigned long long)k1, m);
                u64 o2 = __shfl_xor((unsigned long long)k2, m);
                u64 lo = k1 < o1 ? k1 : o1;
                u64 hi = k1 < o1 ? o1 : k1;
                u64 mn2 = k2 < o2 ? k2 : o2;
                k1 = lo;
                k2 = hi < mn2 ? hi : mn2;
            }
            if ((lane & 15) == 0) {
                const int row = gy * 256 + wm * 128 + rt * 16 + (lane >> 4) * 4 + reg;
                keysA[(size_t)slot * BATCH + row] = k1;
                keysB[(size_t)slot * BATCH + row] = k2;
            }
        }
    }
}

// ---- verify + fused recheck (block-local LDS list); zeroes esum ----
__global__ void k_verify(const u64* __restrict__ keysA, const u64* __restrict__ keysB,
                         const float* __restrict__ x, const float* __restrict__ wT,
                         const float* __restrict__ w2p,
                         int* __restrict__ am, int* __restrict__ counts,
                         float* __restrict__ esum) {
    __shared__ int lrow[256];
    __shared__ int lcc[256];
    __shared__ int lcnt;
    const int t = threadIdx.x;
    const int r = blockIdx.x * 256 + t;
    const int lane = t & 63;

    if (t == 0) lcnt = 0;
    __syncthreads();

    f32x4 z = {0.f, 0.f, 0.f, 0.f};
    ((f32x4*)esum)[r * 2] = z;
    ((f32x4*)esum)[r * 2 + 1] = z;

    u64 m1 = ~0ull, s = ~0ull;
    int i1 = 0;
#pragma unroll
    for (int i = 0; i < 16; ++i) {
        u64 a = keysA[(size_t)i * BATCH + r];
        if (a < m1) { s = m1; m1 = a; i1 = i; }
        else if (a < s) s = a;
    }
    u64 b = keysB[(size_t)i1 * BATCH + r];
    u64 m2 = s < b ? s : b;

    const float d1 = dec_key((uint)(m1 >> 32));
    const float d2 = dec_key((uint)(m2 >> 32));
    const int c1 = (int)(uint)m1 & 1023;
    const int c2 = (int)(uint)m2 & 1023;

    if (d2 - d1 > MARGIN) {
        am[r] = c1;
        atomicAdd(&counts[c1], 1);
    } else {
        int p = atomicAdd(&lcnt, 1);
        lrow[p] = r;
        lcc[p] = (c1 << 10) | c2;
    }
    __syncthreads();

    const int n = lcnt;
    for (int idx = t >> 6; idx < n; idx += 4) {
        const int r2 = lrow[idx];
        const int cc1 = lcc[idx] >> 10;
        const int cc2 = lcc[idx] & 1023;
        const f32x4 x0 = *(const f32x4*)&x[(size_t)r2 * VEC + lane * 8];
        const f32x4 x1 = *(const f32x4*)&x[(size_t)r2 * VEC + lane * 8 + 4];
        float d[2];
        const int cand[2] = {cc1, cc2};
#pragma unroll
        for (int j = 0; j < 2; ++j) {
            const int c = cand[j];
            const f32x4 w0 = *(const f32x4*)&wT[(size_t)c * VEC + lane * 8];
            const f32x4 w1 = *(const f32x4*)&wT[(size_t)c * VEC + lane * 8 + 4];
            float p = x0[0] * w0[0] + x0[1] * w0[1] + x0[2] * w0[2] + x0[3] * w0[3]
                    + x1[0] * w1[0] + x1[1] * w1[1] + x1[2] * w1[2] + x1[3] * w1[3];
#pragma unroll
            for (int m = 1; m < 64; m <<= 1) p += __shfl_xor(p, m);
            float w2 = 0.f;
#pragma unroll
            for (int q = 0; q < 8; ++q) w2 += w2p[q * K + c];
            d[j] = w2 - 2.0f * p;
        }
        const int win = (d[0] < d[1] || (d[0] == d[1] && cc1 < cc2)) ? cc1 : cc2;
        if (lane == 0) {
            am[r2] = win;
            atomicAdd(&counts[win], 1);
        }
    }
}

// ---- scatter with inline (redundant, deterministic) exclusive scan ----
__launch_bounds__(1024)
__global__ void k_scatter(const int* __restrict__ counts, const int* __restrict__ am,
                          int* __restrict__ cursor, int* __restrict__ sorted,
                          int* __restrict__ sortedk) {
    __shared__ int soff[K];
    __shared__ int wsum[16];
    const int t = threadIdx.x;
    const int lane = t & 63, wid = t >> 6;

    const int c = counts[t];
    int s = c;
#pragma unroll
    for (int d = 1; d < 64; d <<= 1) {
        int o = __shfl_up(s, d);
        if (lane >= d) s += o;
    }
    if (lane == 63) wsum[wid] = s;
    __syncthreads();
    if (wid == 0 && lane < 16) {
        int v = wsum[lane];
#pragma unroll
        for (int d = 1; d < 16; d <<= 1) {
            int o = __shfl_up(v, d);
            if (lane >= d) v += o;
        }
        wsum[lane] = v;
    }
    __syncthreads();
    soff[t] = (wid ? wsum[wid - 1] : 0) + s - c;
    __syncthreads();

    const int r = blockIdx.x * 1024 + t;
    const int k = am[r];
    const int pos = atomicAdd(&cursor[k], 1);
    sorted[soff[k] + pos] = r;
    sortedk[soff[k] + pos] = k;
}

// ---- balanced segmented reduction: 32 sorted rows per block ----
__launch_bounds__(512)
__global__ void k_segred(const float* __restrict__ x, const int* __restrict__ sorted,
                         const int* __restrict__ sortedk, float* __restrict__ esum) {
    __shared__ int srow[SEG];
    __shared__ int skid[SEG];
    const int b = blockIdx.x;
    const int t = threadIdx.x;
    if (t < SEG) {
        srow[t] = sorted[b * SEG + t];
        skid[t] = sortedk[b * SEG + t];
    }
    __syncthreads();

    float a = 0.f;
    int cur = skid[0];
#pragma unroll 8
    for (int i = 0; i < SEG; ++i) {
        const int k = skid[i];
        if (k != cur) {
            atomicAdd(&esum[(size_t)cur * VEC + t], a);
            a = 0.f;
            cur = k;
        }
        a += x[(size_t)srow[i] * VEC + t];
    }
    atomicAdd(&esum[(size_t)cur * VEC + t], a);
}

// ---- finalize: inline cs computation + transpose + EMA + normalize ----
__launch_bounds__(256)
__global__ void k_finalize(const float* __restrict__ esum, const float* __restrict__ embed_avg,
                           const int* __restrict__ counts,
                           const float* __restrict__ cluster_size,
                           float* __restrict__ out) {
    __shared__ float tile[64][65];
    __shared__ float wred[4];
    const int t = threadIdx.x;
    const int k0 = blockIdx.x * 64;
    const int v0 = blockIdx.y * 64;
    const int c = t & 63;
    const int r0 = t >> 6;
    const int lane = t & 63, wid = t >> 6;

    float part = 0.f;
#pragma unroll
    for (int j = 0; j < 4; ++j) {
        const int idx = t * 4 + j;
        const int cv = counts[idx];
        part += GAMMA * cluster_size[idx] + (1.0f - GAMMA) * ((cv == 0) ? 1.0f : (float)cv);
    }
#pragma unroll
    for (int d = 32; d > 0; d >>= 1) part += __shfl_xor(part, d);
    if (lane == 0) wred[wid] = part;

#pragma unroll
    for (int j = 0; j < 16; ++j) {
        const int r = r0 + j * 4;
        tile[r][c] = esum[(size_t)(k0 + r) * VEC + v0 + c];
    }
    __syncthreads();

    const float n = (wred[0] + wred[1]) + (wred[2] + wred[3]);
    const int kc = k0 + c;
    const int cv = counts[kc];
    const float ncs = GAMMA * cluster_size[kc] + (1.0f - GAMMA) * ((cv == 0) ? 1.0f : (float)cv);
    const float csk = (ncs + EPS) / (n + (float)K * EPS) * n;

#pragma unroll
    for (int j = 0; j < 16; ++j) {
        const int r = r0 + j * 4;
        const size_t o = (size_t)(v0 + r) * K + k0 + c;
        out[o] = (GAMMA * embed_avg[o] + (1.0f - GAMMA) * tile[c][r]) / csk;
    }
}

extern "C" void kernel_launch(void* const* d_in, const int* in_sizes, int n_in,
                              void* d_out, int out_size, void* d_ws, size_t ws_size,
                              hipStream_t stream) {
    const float* x            = (const float*)d_in[0];   // (BATCH, VEC)
    const float* w            = (const float*)d_in[1];   // (VEC, K)
    const float* cluster_size = (const float*)d_in[2];   // (K,)
    const float* embed_avg    = (const float*)d_in[3];   // (VEC, K)
    float* out = (float*)d_out;                          // (VEC, K)

    // ws layout (~22 MB)
    u64*   keysA   = (u64*)d_ws;                          // 16 x BATCH
    u64*   keysB   = keysA + (size_t)16 * BATCH;          // 16 x BATCH
    int*   am      = (int*)(keysB + (size_t)16 * BATCH);  // BATCH
    float* w2p     = (float*)(am + BATCH);                // 8 x K
    int*   cc      = (int*)(w2p + 8 * K);                 // counts K | cursor K
    int*   counts  = cc;
    int*   cursor  = cc + K;
    int*   sorted  = cc + 2 * K;                          // BATCH
    int*   sortedk = sorted + BATCH;                      // BATCH
    float* esum    = (float*)(sortedk + BATCH);           // (K, VEC), 2 MB
    us8*   wpk     = (us8*)(esum + (size_t)K * VEC);      // 1 MB (32 x 2048)
    float* wT      = (float*)(wpk + (size_t)32 * TG);     // (K, VEC), 2 MB

    k_pack<<<32, 256, 0, stream>>>(w, wpk, wT, w2p, cc);
    k_gemm<<<1024, 512, 0, stream>>>(x, wpk, w2p, keysA, keysB);
    k_verify<<<BATCH / 256, 256, 0, stream>>>(keysA, keysB, x, wT, w2p, am, counts, esum);
    k_scatter<<<64, 1024, 0, stream>>>(counts, am, cursor, sorted, sortedk);
    k_segred<<<BATCH / SEG, 512, 0, stream>>>(x, sorted, sortedk, esum);
    k_finalize<<<dim3(K / 64, VEC / 64), 256, 0, stream>>>(esum, embed_avg, counts, cluster_size, out);
}